// Round 9
// baseline (124.380 us; speedup 1.0000x reference)
//
#include <hip/hip_runtime.h>
#include <hip/hip_bf16.h>

#define DIN  256
#define DOUT 256
#define KNEI 16

typedef __attribute__((ext_vector_type(4))) float f32x4;
typedef __attribute__((ext_vector_type(8))) short bf16x8;
typedef __attribute__((ext_vector_type(4))) short bf16x4;
typedef __attribute__((address_space(1))) const char glb_char;
typedef __attribute__((address_space(3))) char lds_char;

__device__ __forceinline__ short f2bf(float f) {
    unsigned int u;
    __builtin_memcpy(&u, &f, 4);
    unsigned int r = (u + 0x7fffu + ((u >> 16) & 1u)) >> 16;
    return (short)r;
}

__device__ __forceinline__ float bf2f(short s) {
    unsigned int u = ((unsigned int)(unsigned short)s) << 16;
    float f;
    __builtin_memcpy(&f, &u, 4);
    return f;
}

// ---------------------------------------------------------------------------
// K0: pack W into bf16 MFMA fragment layout (blocks 0..31) + zero src bitmap
// (blocks 32..). Fragment (cb,kb): lane l holds
// W[col = cb*16 + (l&15)][k = kb*32 + (l>>4)*8 + j], j=0..7.
// ---------------------------------------------------------------------------
__global__ __launch_bounds__(256) void pack_w_kernel(
        const float* __restrict__ W, short* __restrict__ Wp,
        unsigned char* __restrict__ bm, int N) {
    if (blockIdx.x < 32) {
        int gid  = blockIdx.x * 256 + threadIdx.x;
        int lane = gid & 63;
        int frag = gid >> 6;                     // 0..127
        int kb   = frag & 7;
        int cb   = frag >> 3;
        int col  = cb * 16 + (lane & 15);
        int k0   = kb * 32 + (lane >> 4) * 8;
        const float* src = W + (size_t)col * DIN + k0;
        bf16x8 v;
#pragma unroll
        for (int j = 0; j < 8; ++j) v[j] = f2bf(src[j]);
        *((bf16x8*)Wp + (size_t)frag * 64 + lane) = v;
    } else {
        int i = (blockIdx.x - 32) * 256 + threadIdx.x;
        if (i < N) bm[i] = 0;
    }
}

__global__ __launch_bounds__(256) void set_bm_kernel(
        const int* __restrict__ src_idx, unsigned char* __restrict__ bm, int S) {
    int s = blockIdx.x * 256 + threadIdx.x;
    if (s < S) bm[src_idx[s]] = 1;
}

// ---------------------------------------------------------------------------
// K1: supports = wv @ W^T + b  (bf16 MFMA, f32 accumulate)
// 32-row x 256-col tiles, 8 waves/block (512 thr); each wave owns 32 output
// cols -> wfrag = 16 fragments = 64 VGPRs. Total demand ~120 <= 128-reg
// budget of __launch_bounds__(512,4) -> no spills. Double-buffered 2x32KB
// LDS staged via global_load_lds; pre-swizzled global source, linear LDS
// dest, swizzled ds_read (G21). One __syncthreads per iter; stage(t+1)
// overlaps compute(t).
// ---------------------------------------------------------------------------
__global__ __launch_bounds__(512, 4) void gemm_kernel(
        const float* __restrict__ A, const short* __restrict__ Wp,
        const float* __restrict__ bias, float* __restrict__ out,
        short* __restrict__ out_bf, const unsigned char* __restrict__ bm,
        int M, int use_bm) {
    __shared__ f32x4 lds0[2048];   // 32 KB
    __shared__ f32x4 lds1[2048];   // 32 KB
    const int tid  = threadIdx.x;
    const int wid  = tid >> 6;     // wave id = persistent col-block 0..7
    const int lane = tid & 63;
    const int g    = lane >> 4;
    const int rl   = lane & 15;
    const int nt   = M >> 5;       // 32-row tiles (M multiple of 32)

    int t = blockIdx.x;
    const int stride = gridDim.x;
    if (t >= nt) return;

    // ---- persistent W fragments for this wave's 32 output cols (64 VGPR) ----
    const bf16x8* wp = (const bf16x8*)Wp;
    bf16x8 wfrag[8][2];
#pragma unroll
    for (int kb = 0; kb < 8; ++kb)
#pragma unroll
        for (int j = 0; j < 2; ++j)
            wfrag[kb][j] = wp[(size_t)(((wid * 2 + j) * 8) + kb) * 64 + lane];
    asm volatile("" ::
        "v"(wfrag[0][0]), "v"(wfrag[0][1]), "v"(wfrag[1][0]), "v"(wfrag[1][1]),
        "v"(wfrag[2][0]), "v"(wfrag[2][1]), "v"(wfrag[3][0]), "v"(wfrag[3][1]),
        "v"(wfrag[4][0]), "v"(wfrag[4][1]), "v"(wfrag[5][0]), "v"(wfrag[5][1]),
        "v"(wfrag[6][0]), "v"(wfrag[6][1]), "v"(wfrag[7][0]), "v"(wfrag[7][1]));

    f32x4 biasv[2];
#pragma unroll
    for (int j = 0; j < 2; ++j)
        biasv[j] = *(const f32x4*)(bias + wid * 32 + j * 16 + g * 4);

    char* bufA = (char*)lds0;      // compute buffer
    char* bufB = (char*)lds1;      // stage buffer

    // ---- stage first tile into bufA (4 DMAs/wave, 32 rows total) ----
#pragma unroll
    for (int m = 0; m < 4; ++m) {
        int rloc = m * 8 + wid;
        int grow = t * 32 + rloc;
        const char* src = (const char*)(A + (size_t)grow * DIN)
                        + ((lane ^ (rloc & 7)) << 4);
        __builtin_amdgcn_global_load_lds(
            (const glb_char*)src, (lds_char*)(bufA + rloc * 1024), 16, 0, 0);
    }

    for (;;) {
        __syncthreads();           // vmcnt(0)+lgkmcnt(0) drain + barrier

        int tn = t + stride;
        if (tn < nt) {             // stage next tile (overlaps compute below)
#pragma unroll
            for (int m = 0; m < 4; ++m) {
                int rloc = m * 8 + wid;
                int grow = tn * 32 + rloc;
                const char* src = (const char*)(A + (size_t)grow * DIN)
                                + ((lane ^ (rloc & 7)) << 4);
                __builtin_amdgcn_global_load_lds(
                    (const glb_char*)src, (lds_char*)(bufB + rloc * 1024),
                    16, 0, 0);
            }
        }

        // ---- compute tile t from bufA ----
        f32x4 acc[2][2];
#pragma unroll
        for (int i = 0; i < 2; ++i)
#pragma unroll
            for (int j = 0; j < 2; ++j) acc[i][j] = f32x4{0.f, 0.f, 0.f, 0.f};

#pragma unroll
        for (int kb = 0; kb < 8; ++kb) {
            bf16x8 af[2];
#pragma unroll
            for (int i = 0; i < 2; ++i) {
                int rr   = i * 16 + rl;
                int slot = (kb * 8 + g * 2) ^ (rr & 7);   // swizzled chunk
                const char* base = bufA + rr * 1024;
                f32x4 lo = *(const f32x4*)(base + slot * 16);
                f32x4 hi = *(const f32x4*)(base + (slot ^ 1) * 16);
#pragma unroll
                for (int q = 0; q < 4; ++q) {
                    af[i][q]     = f2bf(lo[q]);
                    af[i][4 + q] = f2bf(hi[q]);
                }
            }
#pragma unroll
            for (int i = 0; i < 2; ++i)
#pragma unroll
                for (int j = 0; j < 2; ++j)
                    acc[i][j] = __builtin_amdgcn_mfma_f32_16x16x32_bf16(
                        wfrag[kb][j], af[i], acc[i][j], 0, 0, 0);
        }

        // ---- epilogue: lane holds row=i*16+rl, douts wid*32+j*16+g*4.. ----
#pragma unroll
        for (int i = 0; i < 2; ++i) {
            int  r  = t * 32 + i * 16 + rl;
            bool sf = (!use_bm || bm[r] == 0);
            float* orow = out    + (size_t)r * DOUT;
            short* brow = out_bf + (size_t)r * DOUT;
#pragma unroll
            for (int j = 0; j < 2; ++j) {
                int c0 = wid * 32 + j * 16 + g * 4;
                f32x4 v = acc[i][j] + biasv[j];
                bf16x4 h;
#pragma unroll
                for (int q = 0; q < 4; ++q) h[q] = f2bf(v[q]);
                *(bf16x4*)(brow + c0) = h;
                if (sf) *(f32x4*)(orow + c0) = v;
            }
        }

        if (tn >= nt) break;
        t = tn;
        char* tmp = bufA; bufA = bufB; bufB = tmp;
    }
}

// ---------------------------------------------------------------------------
// K2 (fused): per source row s (one wave). Each bf16x8 gather covers TWO
// neighbor rows (half-wave each) -> 8 gathers for 16 neighbors + 1 src read.
// ALL nine loads are issued, then ONE asm fence takes all nine results as
// inputs: every load must be issued before the single fence point and all
// results are simultaneously live -> true 9-deep MLP. (Round-8 post-mortem:
// per-value pins serialize — volatile asms are ordered, so the scheduler
// emitted load0-wait-load1-wait...; VGPR stayed 48 and perf was flat.)
// __launch_bounds__(256,4): 128-reg budget so the ~100-reg working set
// doesn't spill.
//   out[src_idx[s]] = sv + leaky(sum_k m_k*neigh_k + sv)
// Race-free: src_idx unique; all gathers hit the immutable bf16 shadow.
// ---------------------------------------------------------------------------
__global__ __launch_bounds__(256, 4) void aggregate_fused_kernel(
        const short* __restrict__ sup_bf, const int* __restrict__ src_idx,
        const int* __restrict__ neighs, const float* __restrict__ mask,
        float* __restrict__ out, int S) {
    int s = blockIdx.x * 4 + (threadIdx.x >> 6);
    if (s >= S) return;
    s = __builtin_amdgcn_readfirstlane(s);
    const int lane = threadIdx.x & 63;
    const int half = lane >> 5;          // which of the 2 rows per gather
    const int c8   = (lane & 31) * 8;    // 8 bf16 columns per lane

    int   idxs[KNEI / 2];
    float ms[KNEI / 2];
#pragma unroll
    for (int k2 = 0; k2 < KNEI / 2; ++k2) {
        idxs[k2] = neighs[(size_t)s * KNEI + k2 * 2 + half];
        ms[k2]   = mask[(size_t)s * KNEI + k2 * 2 + half];
    }
    int srow = src_idx[s];

    // ---- issue ALL row gathers, then one fence over all results ----
    bf16x8 gv[KNEI / 2];
#pragma unroll
    for (int k2 = 0; k2 < KNEI / 2; ++k2)
        gv[k2] = *(const bf16x8*)(sup_bf + (size_t)idxs[k2] * DOUT + c8);
    bf16x8 svv = *(const bf16x8*)(sup_bf + (size_t)srow * DOUT + c8);
    asm volatile("" ::
        "v"(gv[0]), "v"(gv[1]), "v"(gv[2]), "v"(gv[3]),
        "v"(gv[4]), "v"(gv[5]), "v"(gv[6]), "v"(gv[7]), "v"(svv));

    float acc[8] = {0.f, 0.f, 0.f, 0.f, 0.f, 0.f, 0.f, 0.f};
#pragma unroll
    for (int k2 = 0; k2 < KNEI / 2; ++k2)
#pragma unroll
        for (int q = 0; q < 8; ++q) acc[q] += ms[k2] * bf2f(gv[k2][q]);

#pragma unroll
    for (int q = 0; q < 8; ++q) acc[q] += __shfl_xor(acc[q], 32, 64);

    f32x4 r0, r1;
#pragma unroll
    for (int q = 0; q < 8; ++q) {
        float sv = bf2f(svv[q]);
        float o  = acc[q] + sv;
        o = (o >= 0.f) ? o : 0.2f * o;
        float res = sv + o;
        if (q < 4) r0[q] = res; else r1[q - 4] = res;
    }
    if (half == 0) {
        float* dst = out + (size_t)srow * DOUT + c8;
        *(f32x4*)dst       = r0;
        *(f32x4*)(dst + 4) = r1;
    }
}

// ---------------------------------------------------------------------------
// Fallback path (ws too small for bf16 shadow).
// ---------------------------------------------------------------------------
__global__ __launch_bounds__(256) void aggregate_f32_kernel(
        const float* __restrict__ supports, const int* __restrict__ src_idx,
        const int* __restrict__ neighs, const float* __restrict__ mask,
        float* __restrict__ outrows, int S) {
    int s = blockIdx.x * 4 + (threadIdx.x >> 6);
    if (s >= S) return;
    s = __builtin_amdgcn_readfirstlane(s);
    const int lane = threadIdx.x & 63;
    const int c4   = lane * 4;
    f32x4 acc = {0.f, 0.f, 0.f, 0.f};
#pragma unroll
    for (int k = 0; k < KNEI; ++k) {
        int   idx = neighs[(size_t)s * KNEI + k];
        float m   = mask[(size_t)s * KNEI + k];
        f32x4 v = *(const f32x4*)(supports + (size_t)idx * DOUT + c4);
#pragma unroll
        for (int j = 0; j < 4; ++j) acc[j] += m * v[j];
    }
    int srow = src_idx[s];
    f32x4 sv = *(const f32x4*)(supports + (size_t)srow * DOUT + c4);
    f32x4 res;
#pragma unroll
    for (int j = 0; j < 4; ++j) {
        float o = acc[j] + sv[j];
        o = (o >= 0.f) ? o : 0.2f * o;
        res[j] = sv[j] + o;
    }
    *(f32x4*)(outrows + (size_t)s * DOUT + c4) = res;
}

__global__ __launch_bounds__(256) void scatter_kernel(
        const float* __restrict__ outrows, const int* __restrict__ src_idx,
        float* __restrict__ out, int S) {
    int gid = blockIdx.x * 256 + threadIdx.x;
    int s   = gid >> 6;
    if (s >= S) return;
    int lane = gid & 63;
    int row  = src_idx[s];
    *(f32x4*)(out + (size_t)row * DOUT + lane * 4) =
        *(const f32x4*)(outrows + (size_t)s * DOUT + lane * 4);
}

extern "C" void kernel_launch(void* const* d_in, const int* in_sizes, int n_in,
                              void* d_out, int out_size, void* d_ws, size_t ws_size,
                              hipStream_t stream) {
    (void)n_in; (void)out_size;
    const float* wv     = (const float*)d_in[0];
    const int*   src_i  = (const int*)d_in[1];
    const int*   neighs = (const int*)d_in[2];
    const float* mask   = (const float*)d_in[3];
    const float* W      = (const float*)d_in[4];
    const float* bias   = (const float*)d_in[5];
    float* out = (float*)d_out;

    const int N = in_sizes[0] / DIN;   // 100000
    const int S = in_sizes[1];         // 50000

    // ws layout: [Wp bf16 128KB][bm N bytes][shadow bf16 N*256 | outrows f32]
    char*  ws      = (char*)d_ws;
    size_t sz_wp   = (size_t)DOUT * DIN * 2;
    size_t off_bm  = (sz_wp + 1023) & ~(size_t)1023;
    size_t off_buf = (off_bm + (size_t)N + 1023) & ~(size_t)1023;
    short*         Wp      = (short*)ws;
    unsigned char* bm      = (unsigned char*)(ws + off_bm);
    short*         sup_bf  = (short*)(ws + off_buf);
    float*         outrows = (float*)(ws + off_buf);
    int fused = (ws_size >= off_buf + (size_t)N * DOUT * 2) ? 1 : 0;

    int zblocks = (N + 255) / 256;
    pack_w_kernel<<<32 + zblocks, 256, 0, stream>>>(W, Wp, bm, N);
    if (fused)
        set_bm_kernel<<<(S + 255) / 256, 256, 0, stream>>>(src_i, bm, S);

    int nt      = N >> 5;              // 3125 (N multiple of 32)
    int gblocks = nt < 512 ? nt : 512;
    gemm_kernel<<<gblocks, 512, 0, stream>>>(
        wv, Wp, bias, out, sup_bf, bm, N, fused);

    if (fused) {
        aggregate_fused_kernel<<<(S + 3) / 4, 256, 0, stream>>>(
            sup_bf, src_i, neighs, mask, out, S);
    } else {
        aggregate_f32_kernel<<<(S + 3) / 4, 256, 0, stream>>>(
            out, src_i, neighs, mask, outrows, S);
        scatter_kernel<<<((size_t)S * 64 + 255) / 256, 256, 0, stream>>>(
            outrows, src_i, out, S);
    }
}

// Round 10
// 119.979 us; speedup vs baseline: 1.0367x; 1.0367x over previous
//
#include <hip/hip_runtime.h>
#include <hip/hip_bf16.h>

#define DIN  256
#define DOUT 256
#define KNEI 16

typedef __attribute__((ext_vector_type(4))) float f32x4;
typedef __attribute__((ext_vector_type(8))) short bf16x8;
typedef __attribute__((ext_vector_type(4))) short bf16x4;
typedef __attribute__((address_space(1))) const char glb_char;
typedef __attribute__((address_space(3))) char lds_char;

__device__ __forceinline__ short f2bf(float f) {
    unsigned int u;
    __builtin_memcpy(&u, &f, 4);
    unsigned int r = (u + 0x7fffu + ((u >> 16) & 1u)) >> 16;
    return (short)r;
}

__device__ __forceinline__ float bf2f(short s) {
    unsigned int u = ((unsigned int)(unsigned short)s) << 16;
    float f;
    __builtin_memcpy(&f, &u, 4);
    return f;
}

// ---------------------------------------------------------------------------
// K0: pack W into bf16 MFMA fragment layout (blocks 0..31) + zero src bitmap
// (blocks 32..). Fragment (cb,kb): lane l holds
// W[col = cb*16 + (l&15)][k = kb*32 + (l>>4)*8 + j], j=0..7.
// ---------------------------------------------------------------------------
__global__ __launch_bounds__(256) void pack_w_kernel(
        const float* __restrict__ W, short* __restrict__ Wp,
        unsigned char* __restrict__ bm, int N) {
    if (blockIdx.x < 32) {
        int gid  = blockIdx.x * 256 + threadIdx.x;
        int lane = gid & 63;
        int frag = gid >> 6;                     // 0..127
        int kb   = frag & 7;
        int cb   = frag >> 3;
        int col  = cb * 16 + (lane & 15);
        int k0   = kb * 32 + (lane >> 4) * 8;
        const float* src = W + (size_t)col * DIN + k0;
        bf16x8 v;
#pragma unroll
        for (int j = 0; j < 8; ++j) v[j] = f2bf(src[j]);
        *((bf16x8*)Wp + (size_t)frag * 64 + lane) = v;
    } else {
        int i = (blockIdx.x - 32) * 256 + threadIdx.x;
        if (i < N) bm[i] = 0;
    }
}

__global__ __launch_bounds__(256) void set_bm_kernel(
        const int* __restrict__ src_idx, unsigned char* __restrict__ bm, int S) {
    int s = blockIdx.x * 256 + threadIdx.x;
    if (s < S) bm[src_idx[s]] = 1;
}

// ---------------------------------------------------------------------------
// K1: supports = wv @ W^T + b  (bf16 MFMA, f32 accumulate)  — UNCHANGED (r8):
// near its write-roofline (~35-40us vs ~33us floor).
// ---------------------------------------------------------------------------
__global__ __launch_bounds__(512, 4) void gemm_kernel(
        const float* __restrict__ A, const short* __restrict__ Wp,
        const float* __restrict__ bias, float* __restrict__ out,
        short* __restrict__ out_bf, const unsigned char* __restrict__ bm,
        int M, int use_bm) {
    __shared__ f32x4 lds0[2048];   // 32 KB
    __shared__ f32x4 lds1[2048];   // 32 KB
    const int tid  = threadIdx.x;
    const int wid  = tid >> 6;     // wave id = persistent col-block 0..7
    const int lane = tid & 63;
    const int g    = lane >> 4;
    const int rl   = lane & 15;
    const int nt   = M >> 5;       // 32-row tiles (M multiple of 32)

    int t = blockIdx.x;
    const int stride = gridDim.x;
    if (t >= nt) return;

    const bf16x8* wp = (const bf16x8*)Wp;
    bf16x8 wfrag[8][2];
#pragma unroll
    for (int kb = 0; kb < 8; ++kb)
#pragma unroll
        for (int j = 0; j < 2; ++j)
            wfrag[kb][j] = wp[(size_t)(((wid * 2 + j) * 8) + kb) * 64 + lane];
    asm volatile("" ::
        "v"(wfrag[0][0]), "v"(wfrag[0][1]), "v"(wfrag[1][0]), "v"(wfrag[1][1]),
        "v"(wfrag[2][0]), "v"(wfrag[2][1]), "v"(wfrag[3][0]), "v"(wfrag[3][1]),
        "v"(wfrag[4][0]), "v"(wfrag[4][1]), "v"(wfrag[5][0]), "v"(wfrag[5][1]),
        "v"(wfrag[6][0]), "v"(wfrag[6][1]), "v"(wfrag[7][0]), "v"(wfrag[7][1]));

    f32x4 biasv[2];
#pragma unroll
    for (int j = 0; j < 2; ++j)
        biasv[j] = *(const f32x4*)(bias + wid * 32 + j * 16 + g * 4);

    char* bufA = (char*)lds0;
    char* bufB = (char*)lds1;

#pragma unroll
    for (int m = 0; m < 4; ++m) {
        int rloc = m * 8 + wid;
        int grow = t * 32 + rloc;
        const char* src = (const char*)(A + (size_t)grow * DIN)
                        + ((lane ^ (rloc & 7)) << 4);
        __builtin_amdgcn_global_load_lds(
            (const glb_char*)src, (lds_char*)(bufA + rloc * 1024), 16, 0, 0);
    }

    for (;;) {
        __syncthreads();

        int tn = t + stride;
        if (tn < nt) {
#pragma unroll
            for (int m = 0; m < 4; ++m) {
                int rloc = m * 8 + wid;
                int grow = tn * 32 + rloc;
                const char* src = (const char*)(A + (size_t)grow * DIN)
                                + ((lane ^ (rloc & 7)) << 4);
                __builtin_amdgcn_global_load_lds(
                    (const glb_char*)src, (lds_char*)(bufB + rloc * 1024),
                    16, 0, 0);
            }
        }

        f32x4 acc[2][2];
#pragma unroll
        for (int i = 0; i < 2; ++i)
#pragma unroll
            for (int j = 0; j < 2; ++j) acc[i][j] = f32x4{0.f, 0.f, 0.f, 0.f};

#pragma unroll
        for (int kb = 0; kb < 8; ++kb) {
            bf16x8 af[2];
#pragma unroll
            for (int i = 0; i < 2; ++i) {
                int rr   = i * 16 + rl;
                int slot = (kb * 8 + g * 2) ^ (rr & 7);
                const char* base = bufA + rr * 1024;
                f32x4 lo = *(const f32x4*)(base + slot * 16);
                f32x4 hi = *(const f32x4*)(base + (slot ^ 1) * 16);
#pragma unroll
                for (int q = 0; q < 4; ++q) {
                    af[i][q]     = f2bf(lo[q]);
                    af[i][4 + q] = f2bf(hi[q]);
                }
            }
#pragma unroll
            for (int i = 0; i < 2; ++i)
#pragma unroll
                for (int j = 0; j < 2; ++j)
                    acc[i][j] = __builtin_amdgcn_mfma_f32_16x16x32_bf16(
                        wfrag[kb][j], af[i], acc[i][j], 0, 0, 0);
        }

#pragma unroll
        for (int i = 0; i < 2; ++i) {
            int  r  = t * 32 + i * 16 + rl;
            bool sf = (!use_bm || bm[r] == 0);
            float* orow = out    + (size_t)r * DOUT;
            short* brow = out_bf + (size_t)r * DOUT;
#pragma unroll
            for (int j = 0; j < 2; ++j) {
                int c0 = wid * 32 + j * 16 + g * 4;
                f32x4 v = acc[i][j] + biasv[j];
                bf16x4 h;
#pragma unroll
                for (int q = 0; q < 4; ++q) h[q] = f2bf(v[q]);
                *(bf16x4*)(brow + c0) = h;
                if (sf) *(f32x4*)(orow + c0) = v;
            }
        }

        if (tn >= nt) break;
        t = tn;
        char* tmp = bufA; bufA = bufB; bufB = tmp;
    }
}

// ---------------------------------------------------------------------------
// K2 (fused): per source row s (one wave). Half-wave h handles neighbors
// k = h*8 .. h*8+7 (contiguous -> idx/mask load as int4/f32x4: 4 loads not
// 16). The 8 neighbor gathers + src-row read are ONE volatile asm block:
// 9x global_load_dwordx4 back-to-back + s_waitcnt vmcnt(0). Volatile-asm
// internals cannot be rescheduled -> guaranteed 9-deep MLP (r7 pins and r8
// fence both failed: compiler paired idx-load->gather chains serially,
// VGPR stayed <=48). "=&v" early-clobber: data returns may not alias pending
// address regs. Cross-half sums combined via __shfl_xor(...,32).
//   out[src_idx[s]] = sv + leaky(sum_k m_k*neigh_k + sv)
// Race-free: src_idx unique; all gathers hit the immutable bf16 shadow.
// ---------------------------------------------------------------------------
__global__ __launch_bounds__(256, 4) void aggregate_fused_kernel(
        const short* __restrict__ sup_bf, const int* __restrict__ src_idx,
        const int* __restrict__ neighs, const float* __restrict__ mask,
        float* __restrict__ out, int S) {
    int s = blockIdx.x * 4 + (threadIdx.x >> 6);
    if (s >= S) return;
    s = __builtin_amdgcn_readfirstlane(s);
    const int lane = threadIdx.x & 63;
    const int half = lane >> 5;          // half-wave id: neighbors h*8..h*8+7
    const int c8   = (lane & 31) * 8;    // 8 bf16 columns per lane

    // ---- vectorized idx/mask loads (2+2 loads, broadcast within half) ----
    const int*   nrow = neighs + (size_t)s * KNEI + half * 8;
    const float* mrow = mask   + (size_t)s * KNEI + half * 8;
    int4  ia = *(const int4*)(nrow);
    int4  ib = *(const int4*)(nrow + 4);
    f32x4 ma = *(const f32x4*)(mrow);
    f32x4 mb = *(const f32x4*)(mrow + 4);
    int srow = src_idx[s];

    const short* base = sup_bf + c8;
    const short* p0 = base + (size_t)ia.x * DOUT;
    const short* p1 = base + (size_t)ia.y * DOUT;
    const short* p2 = base + (size_t)ia.z * DOUT;
    const short* p3 = base + (size_t)ia.w * DOUT;
    const short* p4 = base + (size_t)ib.x * DOUT;
    const short* p5 = base + (size_t)ib.y * DOUT;
    const short* p6 = base + (size_t)ib.z * DOUT;
    const short* p7 = base + (size_t)ib.w * DOUT;
    const short* ps = base + (size_t)srow * DOUT;

    bf16x8 g0, g1, g2, g3, g4, g5, g6, g7, gs;
    asm volatile(
        "global_load_dwordx4 %0, %9, off\n\t"
        "global_load_dwordx4 %1, %10, off\n\t"
        "global_load_dwordx4 %2, %11, off\n\t"
        "global_load_dwordx4 %3, %12, off\n\t"
        "global_load_dwordx4 %4, %13, off\n\t"
        "global_load_dwordx4 %5, %14, off\n\t"
        "global_load_dwordx4 %6, %15, off\n\t"
        "global_load_dwordx4 %7, %16, off\n\t"
        "global_load_dwordx4 %8, %17, off\n\t"
        "s_waitcnt vmcnt(0)"
        : "=&v"(g0), "=&v"(g1), "=&v"(g2), "=&v"(g3),
          "=&v"(g4), "=&v"(g5), "=&v"(g6), "=&v"(g7), "=&v"(gs)
        : "v"(p0), "v"(p1), "v"(p2), "v"(p3), "v"(p4),
          "v"(p5), "v"(p6), "v"(p7), "v"(ps));

    float acc[8];
#pragma unroll
    for (int q = 0; q < 8; ++q) {
        acc[q] = ma[0] * bf2f(g0[q]) + ma[1] * bf2f(g1[q])
               + ma[2] * bf2f(g2[q]) + ma[3] * bf2f(g3[q])
               + mb[0] * bf2f(g4[q]) + mb[1] * bf2f(g5[q])
               + mb[2] * bf2f(g6[q]) + mb[3] * bf2f(g7[q]);
    }

#pragma unroll
    for (int q = 0; q < 8; ++q) acc[q] += __shfl_xor(acc[q], 32, 64);

    f32x4 r0, r1;
#pragma unroll
    for (int q = 0; q < 8; ++q) {
        float sv = bf2f(gs[q]);
        float o  = acc[q] + sv;
        o = (o >= 0.f) ? o : 0.2f * o;
        float res = sv + o;
        if (q < 4) r0[q] = res; else r1[q - 4] = res;
    }
    if (half == 0) {
        float* dst = out + (size_t)srow * DOUT + c8;
        *(f32x4*)dst       = r0;
        *(f32x4*)(dst + 4) = r1;
    }
}

// ---------------------------------------------------------------------------
// Fallback path (ws too small for bf16 shadow).
// ---------------------------------------------------------------------------
__global__ __launch_bounds__(256) void aggregate_f32_kernel(
        const float* __restrict__ supports, const int* __restrict__ src_idx,
        const int* __restrict__ neighs, const float* __restrict__ mask,
        float* __restrict__ outrows, int S) {
    int s = blockIdx.x * 4 + (threadIdx.x >> 6);
    if (s >= S) return;
    s = __builtin_amdgcn_readfirstlane(s);
    const int lane = threadIdx.x & 63;
    const int c4   = lane * 4;
    f32x4 acc = {0.f, 0.f, 0.f, 0.f};
#pragma unroll
    for (int k = 0; k < KNEI; ++k) {
        int   idx = neighs[(size_t)s * KNEI + k];
        float m   = mask[(size_t)s * KNEI + k];
        f32x4 v = *(const f32x4*)(supports + (size_t)idx * DOUT + c4);
#pragma unroll
        for (int j = 0; j < 4; ++j) acc[j] += m * v[j];
    }
    int srow = src_idx[s];
    f32x4 sv = *(const f32x4*)(supports + (size_t)srow * DOUT + c4);
    f32x4 res;
#pragma unroll
    for (int j = 0; j < 4; ++j) {
        float o = acc[j] + sv[j];
        o = (o >= 0.f) ? o : 0.2f * o;
        res[j] = sv[j] + o;
    }
    *(f32x4*)(outrows + (size_t)s * DOUT + c4) = res;
}

__global__ __launch_bounds__(256) void scatter_kernel(
        const float* __restrict__ outrows, const int* __restrict__ src_idx,
        float* __restrict__ out, int S) {
    int gid = blockIdx.x * 256 + threadIdx.x;
    int s   = gid >> 6;
    if (s >= S) return;
    int lane = gid & 63;
    int row  = src_idx[s];
    *(f32x4*)(out + (size_t)row * DOUT + lane * 4) =
        *(const f32x4*)(outrows + (size_t)s * DOUT + lane * 4);
}

extern "C" void kernel_launch(void* const* d_in, const int* in_sizes, int n_in,
                              void* d_out, int out_size, void* d_ws, size_t ws_size,
                              hipStream_t stream) {
    (void)n_in; (void)out_size;
    const float* wv     = (const float*)d_in[0];
    const int*   src_i  = (const int*)d_in[1];
    const int*   neighs = (const int*)d_in[2];
    const float* mask   = (const float*)d_in[3];
    const float* W      = (const float*)d_in[4];
    const float* bias   = (const float*)d_in[5];
    float* out = (float*)d_out;

    const int N = in_sizes[0] / DIN;   // 100000
    const int S = in_sizes[1];         // 50000

    // ws layout: [Wp bf16 128KB][bm N bytes][shadow bf16 N*256 | outrows f32]
    char*  ws      = (char*)d_ws;
    size_t sz_wp   = (size_t)DOUT * DIN * 2;
    size_t off_bm  = (sz_wp + 1023) & ~(size_t)1023;
    size_t off_buf = (off_bm + (size_t)N + 1023) & ~(size_t)1023;
    short*         Wp      = (short*)ws;
    unsigned char* bm      = (unsigned char*)(ws + off_bm);
    short*         sup_bf  = (short*)(ws + off_buf);
    float*         outrows = (float*)(ws + off_buf);
    int fused = (ws_size >= off_buf + (size_t)N * DOUT * 2) ? 1 : 0;

    int zblocks = (N + 255) / 256;
    pack_w_kernel<<<32 + zblocks, 256, 0, stream>>>(W, Wp, bm, N);
    if (fused)
        set_bm_kernel<<<(S + 255) / 256, 256, 0, stream>>>(src_i, bm, S);

    int nt      = N >> 5;              // 3125 (N multiple of 32)
    int gblocks = nt < 512 ? nt : 512;
    gemm_kernel<<<gblocks, 512, 0, stream>>>(
        wv, Wp, bias, out, sup_bf, bm, N, fused);

    if (fused) {
        aggregate_fused_kernel<<<(S + 3) / 4, 256, 0, stream>>>(
            sup_bf, src_i, neighs, mask, out, S);
    } else {
        aggregate_f32_kernel<<<(S + 3) / 4, 256, 0, stream>>>(
            out, src_i, neighs, mask, outrows, S);
        scatter_kernel<<<((size_t)S * 64 + 255) / 256, 256, 0, stream>>>(
            outrows, src_i, out, S);
    }
}

// Round 11
// 119.276 us; speedup vs baseline: 1.0428x; 1.0059x over previous
//
#include <hip/hip_runtime.h>
#include <hip/hip_bf16.h>

#define DIN  256
#define DOUT 256
#define KNEI 16

typedef __attribute__((ext_vector_type(4))) float f32x4;
typedef __attribute__((ext_vector_type(8))) short bf16x8;
typedef __attribute__((ext_vector_type(4))) short bf16x4;
typedef __attribute__((address_space(1))) const char glb_char;
typedef __attribute__((address_space(3))) char lds_char;

__device__ __forceinline__ short f2bf(float f) {
    unsigned int u;
    __builtin_memcpy(&u, &f, 4);
    unsigned int r = (u + 0x7fffu + ((u >> 16) & 1u)) >> 16;
    return (short)r;
}

__device__ __forceinline__ float bf2f(short s) {
    unsigned int u = ((unsigned int)(unsigned short)s) << 16;
    float f;
    __builtin_memcpy(&f, &u, 4);
    return f;
}

// ---------------------------------------------------------------------------
// K0: pack W into bf16 MFMA fragment layout (blocks 0..31) + zero src bitmap
// (blocks 32..). Fragment (cb,kb): lane l holds
// W[col = cb*16 + (l&15)][k = kb*32 + (l>>4)*8 + j], j=0..7.
// ---------------------------------------------------------------------------
__global__ __launch_bounds__(256) void pack_w_kernel(
        const float* __restrict__ W, short* __restrict__ Wp,
        unsigned char* __restrict__ bm, int N) {
    if (blockIdx.x < 32) {
        int gid  = blockIdx.x * 256 + threadIdx.x;
        int lane = gid & 63;
        int frag = gid >> 6;                     // 0..127
        int kb   = frag & 7;
        int cb   = frag >> 3;
        int col  = cb * 16 + (lane & 15);
        int k0   = kb * 32 + (lane >> 4) * 8;
        const float* src = W + (size_t)col * DIN + k0;
        bf16x8 v;
#pragma unroll
        for (int j = 0; j < 8; ++j) v[j] = f2bf(src[j]);
        *((bf16x8*)Wp + (size_t)frag * 64 + lane) = v;
    } else {
        int i = (blockIdx.x - 32) * 256 + threadIdx.x;
        if (i < N) bm[i] = 0;
    }
}

__global__ __launch_bounds__(256) void set_bm_kernel(
        const int* __restrict__ src_idx, unsigned char* __restrict__ bm, int S) {
    int s = blockIdx.x * 256 + threadIdx.x;
    if (s < S) bm[src_idx[s]] = 1;
}

// ---------------------------------------------------------------------------
// K1: supports = wv @ W^T + b  (bf16 MFMA, f32 accumulate)  — r8 structure.
// NEW (r11): the f32 out store is NONTEMPORAL — it is dead data for the rest
// of the launch (only the harness reads it after timing), and keeping it out
// of L2/L3 leaves room for A (102MB) + shadow (51MB) to stay L3-resident
// (r10 post-mortem: A+out+shadow = 260MB > 256MB L3 -> thrash; gemm FETCH
// 51MB showed only half of A surviving in L3 across replays).
// ---------------------------------------------------------------------------
__global__ __launch_bounds__(512, 4) void gemm_kernel(
        const float* __restrict__ A, const short* __restrict__ Wp,
        const float* __restrict__ bias, float* __restrict__ out,
        short* __restrict__ out_bf, const unsigned char* __restrict__ bm,
        int M, int use_bm) {
    __shared__ f32x4 lds0[2048];   // 32 KB
    __shared__ f32x4 lds1[2048];   // 32 KB
    const int tid  = threadIdx.x;
    const int wid  = tid >> 6;     // wave id = persistent col-block 0..7
    const int lane = tid & 63;
    const int g    = lane >> 4;
    const int rl   = lane & 15;
    const int nt   = M >> 5;       // 32-row tiles (M multiple of 32)

    int t = blockIdx.x;
    const int stride = gridDim.x;
    if (t >= nt) return;

    const bf16x8* wp = (const bf16x8*)Wp;
    bf16x8 wfrag[8][2];
#pragma unroll
    for (int kb = 0; kb < 8; ++kb)
#pragma unroll
        for (int j = 0; j < 2; ++j)
            wfrag[kb][j] = wp[(size_t)(((wid * 2 + j) * 8) + kb) * 64 + lane];
    asm volatile("" ::
        "v"(wfrag[0][0]), "v"(wfrag[0][1]), "v"(wfrag[1][0]), "v"(wfrag[1][1]),
        "v"(wfrag[2][0]), "v"(wfrag[2][1]), "v"(wfrag[3][0]), "v"(wfrag[3][1]),
        "v"(wfrag[4][0]), "v"(wfrag[4][1]), "v"(wfrag[5][0]), "v"(wfrag[5][1]),
        "v"(wfrag[6][0]), "v"(wfrag[6][1]), "v"(wfrag[7][0]), "v"(wfrag[7][1]));

    f32x4 biasv[2];
#pragma unroll
    for (int j = 0; j < 2; ++j)
        biasv[j] = *(const f32x4*)(bias + wid * 32 + j * 16 + g * 4);

    char* bufA = (char*)lds0;
    char* bufB = (char*)lds1;

#pragma unroll
    for (int m = 0; m < 4; ++m) {
        int rloc = m * 8 + wid;
        int grow = t * 32 + rloc;
        const char* src = (const char*)(A + (size_t)grow * DIN)
                        + ((lane ^ (rloc & 7)) << 4);
        __builtin_amdgcn_global_load_lds(
            (const glb_char*)src, (lds_char*)(bufA + rloc * 1024), 16, 0, 0);
    }

    for (;;) {
        __syncthreads();

        int tn = t + stride;
        if (tn < nt) {
#pragma unroll
            for (int m = 0; m < 4; ++m) {
                int rloc = m * 8 + wid;
                int grow = tn * 32 + rloc;
                const char* src = (const char*)(A + (size_t)grow * DIN)
                                + ((lane ^ (rloc & 7)) << 4);
                __builtin_amdgcn_global_load_lds(
                    (const glb_char*)src, (lds_char*)(bufB + rloc * 1024),
                    16, 0, 0);
            }
        }

        f32x4 acc[2][2];
#pragma unroll
        for (int i = 0; i < 2; ++i)
#pragma unroll
            for (int j = 0; j < 2; ++j) acc[i][j] = f32x4{0.f, 0.f, 0.f, 0.f};

#pragma unroll
        for (int kb = 0; kb < 8; ++kb) {
            bf16x8 af[2];
#pragma unroll
            for (int i = 0; i < 2; ++i) {
                int rr   = i * 16 + rl;
                int slot = (kb * 8 + g * 2) ^ (rr & 7);
                const char* base = bufA + rr * 1024;
                f32x4 lo = *(const f32x4*)(base + slot * 16);
                f32x4 hi = *(const f32x4*)(base + (slot ^ 1) * 16);
#pragma unroll
                for (int q = 0; q < 4; ++q) {
                    af[i][q]     = f2bf(lo[q]);
                    af[i][4 + q] = f2bf(hi[q]);
                }
            }
#pragma unroll
            for (int i = 0; i < 2; ++i)
#pragma unroll
                for (int j = 0; j < 2; ++j)
                    acc[i][j] = __builtin_amdgcn_mfma_f32_16x16x32_bf16(
                        wfrag[kb][j], af[i], acc[i][j], 0, 0, 0);
        }

#pragma unroll
        for (int i = 0; i < 2; ++i) {
            int  r  = t * 32 + i * 16 + rl;
            bool sf = (!use_bm || bm[r] == 0);
            float* orow = out    + (size_t)r * DOUT;
            short* brow = out_bf + (size_t)r * DOUT;
#pragma unroll
            for (int j = 0; j < 2; ++j) {
                int c0 = wid * 32 + j * 16 + g * 4;
                f32x4 v = acc[i][j] + biasv[j];
                bf16x4 h;
#pragma unroll
                for (int q = 0; q < 4; ++q) h[q] = f2bf(v[q]);
                *(bf16x4*)(brow + c0) = h;                     // re-read: cache
                if (sf) __builtin_nontemporal_store(v, (f32x4*)(orow + c0));
            }
        }

        if (tn >= nt) break;
        t = tn;
        char* tmp = bufA; bufA = bufB; bufB = tmp;
    }
}

// ---------------------------------------------------------------------------
// K2 (fused): per source row s (one wave). 8 row-gathers + src read in ONE
// volatile asm block (guaranteed 9-deep MLP — though r10 proved TLP already
// saturates the memory system; kept because it's the cleanest codegen).
// NEW (r11): result store is NONTEMPORAL (dead data; keep L3 for the shadow).
//   out[src_idx[s]] = sv + leaky(sum_k m_k*neigh_k + sv)
// Race-free: src_idx unique; all gathers hit the immutable bf16 shadow.
// ---------------------------------------------------------------------------
__global__ __launch_bounds__(256, 4) void aggregate_fused_kernel(
        const short* __restrict__ sup_bf, const int* __restrict__ src_idx,
        const int* __restrict__ neighs, const float* __restrict__ mask,
        float* __restrict__ out, int S) {
    int s = blockIdx.x * 4 + (threadIdx.x >> 6);
    if (s >= S) return;
    s = __builtin_amdgcn_readfirstlane(s);
    const int lane = threadIdx.x & 63;
    const int half = lane >> 5;          // half-wave id: neighbors h*8..h*8+7
    const int c8   = (lane & 31) * 8;    // 8 bf16 columns per lane

    const int*   nrow = neighs + (size_t)s * KNEI + half * 8;
    const float* mrow = mask   + (size_t)s * KNEI + half * 8;
    int4  ia = *(const int4*)(nrow);
    int4  ib = *(const int4*)(nrow + 4);
    f32x4 ma = *(const f32x4*)(mrow);
    f32x4 mb = *(const f32x4*)(mrow + 4);
    int srow = src_idx[s];

    const short* base = sup_bf + c8;
    const short* p0 = base + (size_t)ia.x * DOUT;
    const short* p1 = base + (size_t)ia.y * DOUT;
    const short* p2 = base + (size_t)ia.z * DOUT;
    const short* p3 = base + (size_t)ia.w * DOUT;
    const short* p4 = base + (size_t)ib.x * DOUT;
    const short* p5 = base + (size_t)ib.y * DOUT;
    const short* p6 = base + (size_t)ib.z * DOUT;
    const short* p7 = base + (size_t)ib.w * DOUT;
    const short* ps = base + (size_t)srow * DOUT;

    bf16x8 g0, g1, g2, g3, g4, g5, g6, g7, gs;
    asm volatile(
        "global_load_dwordx4 %0, %9, off\n\t"
        "global_load_dwordx4 %1, %10, off\n\t"
        "global_load_dwordx4 %2, %11, off\n\t"
        "global_load_dwordx4 %3, %12, off\n\t"
        "global_load_dwordx4 %4, %13, off\n\t"
        "global_load_dwordx4 %5, %14, off\n\t"
        "global_load_dwordx4 %6, %15, off\n\t"
        "global_load_dwordx4 %7, %16, off\n\t"
        "global_load_dwordx4 %8, %17, off\n\t"
        "s_waitcnt vmcnt(0)"
        : "=&v"(g0), "=&v"(g1), "=&v"(g2), "=&v"(g3),
          "=&v"(g4), "=&v"(g5), "=&v"(g6), "=&v"(g7), "=&v"(gs)
        : "v"(p0), "v"(p1), "v"(p2), "v"(p3), "v"(p4),
          "v"(p5), "v"(p6), "v"(p7), "v"(ps));

    float acc[8];
#pragma unroll
    for (int q = 0; q < 8; ++q) {
        acc[q] = ma[0] * bf2f(g0[q]) + ma[1] * bf2f(g1[q])
               + ma[2] * bf2f(g2[q]) + ma[3] * bf2f(g3[q])
               + mb[0] * bf2f(g4[q]) + mb[1] * bf2f(g5[q])
               + mb[2] * bf2f(g6[q]) + mb[3] * bf2f(g7[q]);
    }

#pragma unroll
    for (int q = 0; q < 8; ++q) acc[q] += __shfl_xor(acc[q], 32, 64);

    f32x4 r0, r1;
#pragma unroll
    for (int q = 0; q < 8; ++q) {
        float sv = bf2f(gs[q]);
        float o  = acc[q] + sv;
        o = (o >= 0.f) ? o : 0.2f * o;
        float res = sv + o;
        if (q < 4) r0[q] = res; else r1[q - 4] = res;
    }
    if (half == 0) {
        float* dst = out + (size_t)srow * DOUT + c8;
        __builtin_nontemporal_store(r0, (f32x4*)dst);
        __builtin_nontemporal_store(r1, (f32x4*)(dst + 4));
    }
}

// ---------------------------------------------------------------------------
// Fallback path (ws too small for bf16 shadow).
// ---------------------------------------------------------------------------
__global__ __launch_bounds__(256) void aggregate_f32_kernel(
        const float* __restrict__ supports, const int* __restrict__ src_idx,
        const int* __restrict__ neighs, const float* __restrict__ mask,
        float* __restrict__ outrows, int S) {
    int s = blockIdx.x * 4 + (threadIdx.x >> 6);
    if (s >= S) return;
    s = __builtin_amdgcn_readfirstlane(s);
    const int lane = threadIdx.x & 63;
    const int c4   = lane * 4;
    f32x4 acc = {0.f, 0.f, 0.f, 0.f};
#pragma unroll
    for (int k = 0; k < KNEI; ++k) {
        int   idx = neighs[(size_t)s * KNEI + k];
        float m   = mask[(size_t)s * KNEI + k];
        f32x4 v = *(const f32x4*)(supports + (size_t)idx * DOUT + c4);
#pragma unroll
        for (int j = 0; j < 4; ++j) acc[j] += m * v[j];
    }
    int srow = src_idx[s];
    f32x4 sv = *(const f32x4*)(supports + (size_t)srow * DOUT + c4);
    f32x4 res;
#pragma unroll
    for (int j = 0; j < 4; ++j) {
        float o = acc[j] + sv[j];
        o = (o >= 0.f) ? o : 0.2f * o;
        res[j] = sv[j] + o;
    }
    *(f32x4*)(outrows + (size_t)s * DOUT + c4) = res;
}

__global__ __launch_bounds__(256) void scatter_kernel(
        const float* __restrict__ outrows, const int* __restrict__ src_idx,
        float* __restrict__ out, int S) {
    int gid = blockIdx.x * 256 + threadIdx.x;
    int s   = gid >> 6;
    if (s >= S) return;
    int lane = gid & 63;
    int row  = src_idx[s];
    *(f32x4*)(out + (size_t)row * DOUT + lane * 4) =
        *(const f32x4*)(outrows + (size_t)s * DOUT + lane * 4);
}

extern "C" void kernel_launch(void* const* d_in, const int* in_sizes, int n_in,
                              void* d_out, int out_size, void* d_ws, size_t ws_size,
                              hipStream_t stream) {
    (void)n_in; (void)out_size;
    const float* wv     = (const float*)d_in[0];
    const int*   src_i  = (const int*)d_in[1];
    const int*   neighs = (const int*)d_in[2];
    const float* mask   = (const float*)d_in[3];
    const float* W      = (const float*)d_in[4];
    const float* bias   = (const float*)d_in[5];
    float* out = (float*)d_out;

    const int N = in_sizes[0] / DIN;   // 100000
    const int S = in_sizes[1];         // 50000

    // ws layout: [Wp bf16 128KB][bm N bytes][shadow bf16 N*256 | outrows f32]
    char*  ws      = (char*)d_ws;
    size_t sz_wp   = (size_t)DOUT * DIN * 2;
    size_t off_bm  = (sz_wp + 1023) & ~(size_t)1023;
    size_t off_buf = (off_bm + (size_t)N + 1023) & ~(size_t)1023;
    short*         Wp      = (short*)ws;
    unsigned char* bm      = (unsigned char*)(ws + off_bm);
    short*         sup_bf  = (short*)(ws + off_buf);
    float*         outrows = (float*)(ws + off_buf);
    int fused = (ws_size >= off_buf + (size_t)N * DOUT * 2) ? 1 : 0;

    int zblocks = (N + 255) / 256;
    pack_w_kernel<<<32 + zblocks, 256, 0, stream>>>(W, Wp, bm, N);
    if (fused)
        set_bm_kernel<<<(S + 255) / 256, 256, 0, stream>>>(src_i, bm, S);

    int nt      = N >> 5;              // 3125 (N multiple of 32)
    int gblocks = nt < 512 ? nt : 512;
    gemm_kernel<<<gblocks, 512, 0, stream>>>(
        wv, Wp, bias, out, sup_bf, bm, N, fused);

    if (fused) {
        aggregate_fused_kernel<<<(S + 3) / 4, 256, 0, stream>>>(
            sup_bf, src_i, neighs, mask, out, S);
    } else {
        aggregate_f32_kernel<<<(S + 3) / 4, 256, 0, stream>>>(
            out, src_i, neighs, mask, outrows, S);
        scatter_kernel<<<((size_t)S * 64 + 255) / 256, 256, 0, stream>>>(
            outrows, src_i, out, S);
    }
}